// Round 8
// baseline (257.807 us; speedup 1.0000x reference)
//
#include <hip/hip_runtime.h>

#define NN 50000
#define NE 800000
#define NG 128
#define NF 64
#define EPSV 1e-5f
#define GB3 782     // GEMM blocks = ceil(NN/64)
#define NBUCK 196   // node buckets of 256
#define BCAP 5120   // bucket capacity (mean 4096, sigma~64)

// ======================= zero init (replaces 43us fillBuffer) =======================
__global__ __launch_bounds__(256) void k_zero(int* __restrict__ gcursor,
                                              float* __restrict__ stats) {
  int t = threadIdx.x;
  if (t < NBUCK) gcursor[t] = 0;
  for (int i = t; i < 6 * NG; i += 256) stats[i] = 0.f;
}

// ======================= bucketed CSR build =======================
// Pass A: bin edges by dst>>8 with LDS pre-aggregation (dense appends).
__global__ __launch_bounds__(256) void k_binA(const int* __restrict__ src,
                                              const int* __restrict__ dst,
                                              int* __restrict__ gcursor,
                                              int2* __restrict__ bbuf) {
  __shared__ int cnt[NBUCK], base[NBUCK], rank[NBUCK];
  int tid = threadIdx.x;
  if (tid < NBUCK) { cnt[tid] = 0; rank[tid] = 0; }
  __syncthreads();
  int e0 = blockIdx.x * 4096;
  int sv[16], dv[16], bk[16];
#pragma unroll
  for (int i = 0; i < 16; ++i) {
    int e = e0 + i * 256 + tid;
    if (e < NE) {
      sv[i] = src[e];
      dv[i] = dst[e];
      bk[i] = dv[i] >> 8;
      atomicAdd(&cnt[bk[i]], 1);
    } else bk[i] = -1;
  }
  __syncthreads();
  if (tid < NBUCK && cnt[tid] > 0) base[tid] = atomicAdd(&gcursor[tid], cnt[tid]);
  __syncthreads();
#pragma unroll
  for (int i = 0; i < 16; ++i) {
    if (bk[i] >= 0) {
      int p = base[bk[i]] + atomicAdd(&rank[bk[i]], 1);
      if (p < BCAP) bbuf[(size_t)bk[i] * BCAP + p] = make_int2(sv[i], dv[i]);
    }
  }
}

// scan bucket sizes -> bucket bases; off[NN] = NE
__global__ __launch_bounds__(256) void k_bscan(const int* __restrict__ gcursor,
                                               int* __restrict__ bbase,
                                               int* __restrict__ off) {
  __shared__ int sh[256];
  int tid = threadIdx.x;
  int v = (tid < NBUCK) ? gcursor[tid] : 0;
  sh[tid] = v;
  __syncthreads();
  for (int d = 1; d < 256; d <<= 1) {
    int t = (tid >= d) ? sh[tid - d] : 0;
    __syncthreads();
    sh[tid] += t;
    __syncthreads();
  }
  if (tid < NBUCK) bbase[tid] = sh[tid] - v;
  if (tid == NBUCK - 1) { bbase[NBUCK] = sh[tid]; off[NN] = sh[tid]; }
}

// Pass B: per bucket, local count+scan of 256 nodes, dense csr scatter.
__global__ __launch_bounds__(256) void k_binB(const int2* __restrict__ bbuf,
                                              const int* __restrict__ gcursor,
                                              const int* __restrict__ bbase,
                                              int* __restrict__ off,
                                              int* __restrict__ csr) {
  __shared__ int cnt[256], cur[256], sh[256];
  int tid = threadIdx.x;
  int b = blockIdx.x;
  int nb = gcursor[b]; if (nb > BCAP) nb = BCAP;
  int gbase = bbase[b];
  cnt[tid] = 0;
  __syncthreads();
  const int2* bp = bbuf + (size_t)b * BCAP;
  for (int i = tid; i < nb; i += 256) {
    atomicAdd(&cnt[bp[i].y & 255], 1);
  }
  __syncthreads();
  int v = cnt[tid];
  sh[tid] = v;
  __syncthreads();
  for (int d = 1; d < 256; d <<= 1) {
    int t = (tid >= d) ? sh[tid - d] : 0;
    __syncthreads();
    sh[tid] += t;
    __syncthreads();
  }
  int excl = sh[tid] - v;
  cur[tid] = excl;
  int node = b * 256 + tid;
  if (node < NN) off[node] = gbase + excl;
  __syncthreads();
  for (int i = tid; i < nb; i += 256) {
    int2 e = bp[i];
    int p = atomicAdd(&cur[e.y & 255], 1);
    csr[gbase + p] = e.x;
  }
}

// graph boundaries from sorted batch
__global__ void k_bounds(const int* __restrict__ batch, int* __restrict__ bound) {
  int i = blockIdx.x * 256 + threadIdx.x;
  if (i >= NN) return;
  int b1 = batch[i];
  int b0 = (i == 0) ? -1 : batch[i - 1];
  for (int g = b0 + 1; g <= b1; ++g) bound[g] = i;
  if (i == NN - 1) {
    for (int g = b1 + 1; g <= NG; ++g) bound[g] = NN;
  }
}

// ============ mean aggregation: 16 lanes x float4 per node (4 nodes/wave) ============
__global__ __launch_bounds__(256) void k_agg(const float* __restrict__ in,
                                             const int* __restrict__ off,
                                             const int* __restrict__ csr,
                                             float* __restrict__ out) {
  int t = blockIdx.x * 256 + threadIdx.x;
  int node = t >> 4;
  int fl = (t & 15) << 2;
  if (node >= NN) return;
  int s0 = off[node], s1 = off[node + 1];
  float4 acc = make_float4(0.f, 0.f, 0.f, 0.f);
  for (int j = s0; j < s1; ++j) {
    int s = csr[j];
    float4 v = *(const float4*)&in[s * NF + fl];
    acc.x += v.x; acc.y += v.y; acc.z += v.z; acc.w += v.w;
  }
  float inv = (s1 > s0) ? 1.f / (float)(s1 - s0) : 0.f;
  *(float4*)&out[node * NF + fl] =
      make_float4(acc.x * inv, acc.y * inv, acc.z * inv, acc.w * inv);
}

// ============ dual GEMM: lane=row, wave=16-col slice; fused LN stats ============
__global__ __launch_bounds__(256) void k_sage_linear(const float* __restrict__ A,
                                                     const float* __restrict__ X,
                                                     const float* __restrict__ Wl,
                                                     const float* __restrict__ bl,
                                                     const float* __restrict__ Wr,
                                                     const int* __restrict__ batch,
                                                     float* __restrict__ gsum,
                                                     float* __restrict__ gsq,
                                                     float* __restrict__ out) {
  __shared__ float sh_s[4][64];
  __shared__ float sh_q[4][64];
  __shared__ float gs[NG];
  __shared__ float gq[NG];
  int tid = threadIdx.x;
  int lane = tid & 63;
  int wv = __builtin_amdgcn_readfirstlane(tid >> 6);
  int c0 = wv * 16;
  int row = blockIdx.x * 64 + lane;
  bool valid = row < NN;
  if (tid < NG) { gs[tid] = 0.f; gq[tid] = 0.f; }

  float acc[16];
#pragma unroll
  for (int cc = 0; cc < 16; ++cc) acc[cc] = bl[c0 + cc];

  int rsafe = valid ? row : 0;
  const float4* Ar = (const float4*)(A + (size_t)rsafe * NF);
  const float4* Xr = (const float4*)(X + (size_t)rsafe * NF);

  for (int k4 = 0; k4 < 16; ++k4) {
    float4 av = Ar[k4];
    const float* W0 = Wl + ((k4 * 4 + 0) * NF + c0);
    const float* W1 = Wl + ((k4 * 4 + 1) * NF + c0);
    const float* W2 = Wl + ((k4 * 4 + 2) * NF + c0);
    const float* W3 = Wl + ((k4 * 4 + 3) * NF + c0);
#pragma unroll
    for (int cc = 0; cc < 16; ++cc)
      acc[cc] += av.x * W0[cc] + av.y * W1[cc] + av.z * W2[cc] + av.w * W3[cc];
  }
  for (int k4 = 0; k4 < 16; ++k4) {
    float4 xv = Xr[k4];
    const float* W0 = Wr + ((k4 * 4 + 0) * NF + c0);
    const float* W1 = Wr + ((k4 * 4 + 1) * NF + c0);
    const float* W2 = Wr + ((k4 * 4 + 2) * NF + c0);
    const float* W3 = Wr + ((k4 * 4 + 3) * NF + c0);
#pragma unroll
    for (int cc = 0; cc < 16; ++cc)
      acc[cc] += xv.x * W0[cc] + xv.y * W1[cc] + xv.z * W2[cc] + xv.w * W3[cc];
  }

  if (valid) {
    float4* op = (float4*)(out + (size_t)row * NF + c0);
    op[0] = make_float4(acc[0], acc[1], acc[2], acc[3]);
    op[1] = make_float4(acc[4], acc[5], acc[6], acc[7]);
    op[2] = make_float4(acc[8], acc[9], acc[10], acc[11]);
    op[3] = make_float4(acc[12], acc[13], acc[14], acc[15]);
  }

  float s = 0.f, q = 0.f;
#pragma unroll
  for (int cc = 0; cc < 16; ++cc) { s += acc[cc]; q += acc[cc] * acc[cc]; }
  sh_s[wv][lane] = s;
  sh_q[wv][lane] = q;
  __syncthreads();
  if (tid < 64) {
    float ss = sh_s[0][lane] + sh_s[1][lane] + sh_s[2][lane] + sh_s[3][lane];
    float qq = sh_q[0][lane] + sh_q[1][lane] + sh_q[2][lane] + sh_q[3][lane];
    int r = blockIdx.x * 64 + lane;
    if (r < NN) {
      int g = batch[r];
      atomicAdd(&gs[g], ss);
      atomicAdd(&gq[g], qq);
    }
  }
  __syncthreads();
  if (tid < NG) {
    float fs = gs[tid], fq = gq[tid];
    if (fs != 0.f || fq != 0.f) { atomicAdd(&gsum[tid], fs); atomicAdd(&gsq[tid], fq); }
  }
}

// ============ skip GEMM: out = LN0(t0) [+ LN1(t1)] + X@W  (lane=row) ============
__global__ __launch_bounds__(256) void k_skip_linear(
    const float* __restrict__ X, const float* __restrict__ W,
    const float* __restrict__ t0, const float* __restrict__ gsum0, const float* __restrict__ gsq0,
    const float* __restrict__ lw0, const float* __restrict__ lb0, const float* __restrict__ pa0,
    const float* __restrict__ t1, const float* __restrict__ gsum1, const float* __restrict__ gsq1,
    const float* __restrict__ lw1, const float* __restrict__ lb1, const float* __restrict__ pa1,
    const int* __restrict__ batch, const int* __restrict__ bound,
    float* __restrict__ out) {
  int tid = threadIdx.x;
  int lane = tid & 63;
  int wv = __builtin_amdgcn_readfirstlane(tid >> 6);
  int c0 = wv * 16;
  int row = blockIdx.x * 64 + lane;
  bool valid = row < NN;
  int rsafe = valid ? row : 0;

  float acc[16];
#pragma unroll
  for (int cc = 0; cc < 16; ++cc) acc[cc] = 0.f;

  const float4* Xr = (const float4*)(X + (size_t)rsafe * NF);
  for (int k4 = 0; k4 < 16; ++k4) {
    float4 xv = Xr[k4];
    const float* W0 = W + ((k4 * 4 + 0) * NF + c0);
    const float* W1 = W + ((k4 * 4 + 1) * NF + c0);
    const float* W2 = W + ((k4 * 4 + 2) * NF + c0);
    const float* W3 = W + ((k4 * 4 + 3) * NF + c0);
#pragma unroll
    for (int cc = 0; cc < 16; ++cc)
      acc[cc] += xv.x * W0[cc] + xv.y * W1[cc] + xv.z * W2[cc] + xv.w * W3[cc];
  }

  int g = batch[rsafe];
  float cntf = (float)(bound[g + 1] - bound[g]);
  float norm = fmaxf(cntf, 1.f) * (float)NF;
  {
    float m0 = gsum0[g] / norm;
    float v0 = gsq0[g] / norm - m0 * m0;
    float rs0 = rsqrtf(v0 + EPSV);
    float a0 = pa0[0];
    const float4* T0 = (const float4*)(t0 + (size_t)rsafe * NF + c0);
#pragma unroll
    for (int j = 0; j < 4; ++j) {
      float4 tv = T0[j];
      float tvv[4] = {tv.x, tv.y, tv.z, tv.w};
#pragma unroll
      for (int jj = 0; jj < 4; ++jj) {
        int cc = j * 4 + jj;
        float u = (tvv[jj] - m0) * rs0 * lw0[c0 + cc] + lb0[c0 + cc];
        acc[cc] += (u >= 0.f) ? u : a0 * u;
      }
    }
  }
  if (t1) {
    float m1 = gsum1[g] / norm;
    float v1 = gsq1[g] / norm - m1 * m1;
    float rs1 = rsqrtf(v1 + EPSV);
    float a1 = pa1[0];
    const float4* T1 = (const float4*)(t1 + (size_t)rsafe * NF + c0);
#pragma unroll
    for (int j = 0; j < 4; ++j) {
      float4 tv = T1[j];
      float tvv[4] = {tv.x, tv.y, tv.z, tv.w};
#pragma unroll
      for (int jj = 0; jj < 4; ++jj) {
        int cc = j * 4 + jj;
        float u = (tvv[jj] - m1) * rs1 * lw1[c0 + cc] + lb1[c0 + cc];
        acc[cc] += (u >= 0.f) ? u : a1 * u;
      }
    }
  }

  if (valid) {
    float4* op = (float4*)(out + (size_t)row * NF + c0);
    op[0] = make_float4(acc[0], acc[1], acc[2], acc[3]);
    op[1] = make_float4(acc[4], acc[5], acc[6], acc[7]);
    op[2] = make_float4(acc[8], acc[9], acc[10], acc[11]);
    op[3] = make_float4(acc[12], acc[13], acc[14], acc[15]);
  }
}

// ============ graph LayerNorm apply + affine + PReLU (final layer) ============
__global__ __launch_bounds__(256) void k_ln_apply(const float* __restrict__ t,
                                                  const int* __restrict__ batch,
                                                  const int* __restrict__ bound,
                                                  const float* __restrict__ gsum,
                                                  const float* __restrict__ gsq,
                                                  const float* __restrict__ w,
                                                  const float* __restrict__ b,
                                                  const float* __restrict__ alpha,
                                                  float* __restrict__ out) {
  int wid = (blockIdx.x * 256 + threadIdx.x) >> 6;
  int lane = threadIdx.x & 63;
  if (wid >= NN) return;
  int g = batch[wid];
  float cnt = (float)(bound[g + 1] - bound[g]);
  float norm = fmaxf(cnt, 1.f) * (float)NF;
  float mean = gsum[g] / norm;
  float var = gsq[g] / norm - mean * mean;
  float rstd = rsqrtf(var + EPSV);
  float a = alpha[0];
  float v = t[wid * NF + lane];
  v = (v - mean) * rstd;
  v = v * w[lane] + b[lane];
  out[wid * NF + lane] = (v >= 0.f) ? v : a * v;
}

// ======================= launch =======================
extern "C" void kernel_launch(void* const* d_in, const int* in_sizes, int n_in,
                              void* d_out, int out_size, void* d_ws, size_t ws_size,
                              hipStream_t stream) {
  const float* x     = (const float*)d_in[0];
  const float* c0_Wl = (const float*)d_in[1];
  const float* c0_bl = (const float*)d_in[2];
  const float* c0_Wr = (const float*)d_in[3];
  const float* c1_Wl = (const float*)d_in[4];
  const float* c1_bl = (const float*)d_in[5];
  const float* c1_Wr = (const float*)d_in[6];
  const float* c2_Wl = (const float*)d_in[7];
  const float* c2_bl = (const float*)d_in[8];
  const float* c2_Wr = (const float*)d_in[9];
  const float* s0_W  = (const float*)d_in[10];
  const float* s1_W  = (const float*)d_in[11];
  const float* ln0_w = (const float*)d_in[12];
  const float* ln0_b = (const float*)d_in[13];
  const float* ln1_w = (const float*)d_in[14];
  const float* ln1_b = (const float*)d_in[15];
  const float* ln2_w = (const float*)d_in[16];
  const float* ln2_b = (const float*)d_in[17];
  const float* p0_a  = (const float*)d_in[18];
  const float* p1_a  = (const float*)d_in[19];
  const float* p2_a  = (const float*)d_in[20];
  const int*   ei    = (const int*)d_in[21];   // [2, E] int32
  const int*   batch = (const int*)d_in[22];   // [N] int32
  float* out = (float*)d_out;

  const int* src = ei;
  const int* dst = ei + NE;

  // ---- workspace layout ----
  char* ws = (char*)d_ws;
  const size_t off_gcur   = 0;                          // NBUCK ints
  const size_t off_stats  = 200704;                     // 6*G floats
  const size_t off_bound  = 204800;                     // G+1 ints
  const size_t off_off    = 205824;                     // N+1 ints
  const size_t off_bbase  = 406272;                     // NBUCK+1 ints
  const size_t off_csr    = 607744;                     // E ints
  const size_t off_B1     = 3807744;                    // N*F floats (bbuf aliases)
  const size_t off_B2     = off_B1 + 12800000;
  const size_t off_B3     = off_B2 + 12800000;
  const size_t off_B4     = off_B3 + 12800000;

  int*   gcursor = (int*)(ws + off_gcur);
  float* stats   = (float*)(ws + off_stats);
  int*   bound   = (int*)(ws + off_bound);
  int*   offp    = (int*)(ws + off_off);
  int*   bbase   = (int*)(ws + off_bbase);
  int*   csr     = (int*)(ws + off_csr);
  float* B1      = (float*)(ws + off_B1);   // agg output (after CSR build)
  int2*  bbuf    = (int2*)(ws + off_B1);    // edge buckets (dead after binB)
  float* B2      = (float*)(ws + off_B2);   // h1 (raw pre-LN)
  float* B3      = (float*)(ws + off_B3);   // z
  float* B4      = (float*)(ws + off_B4);   // h2 (raw pre-LN)
  (void)ws_size; (void)in_sizes; (void)n_in; (void)out_size;

  float* gsum0 = stats + 0 * NG; float* gsq0 = stats + 1 * NG;
  float* gsum1 = stats + 2 * NG; float* gsq1 = stats + 3 * NG;
  float* gsum2 = stats + 4 * NG; float* gsq2 = stats + 5 * NG;

  const int NB  = (NN + 255) / 256;            // 196
  const int WB  = (NN * 64 + 255) / 256;       // 12500 (wave-per-node)
  const int AB  = (NN * 16 + 255) / 256;       // 3125  (agg: 16 lanes/node)

  // zero init (replaces pathological 43us fillBuffer memset)
  k_zero<<<1, 256, 0, stream>>>(gcursor, stats);

  // bucketed CSR build (once, reused by all 3 layers)
  k_binA<<<NBUCK, 256, 0, stream>>>(src, dst, gcursor, bbuf);
  k_bscan<<<1, 256, 0, stream>>>(gcursor, bbase, offp);
  k_binB<<<NBUCK, 256, 0, stream>>>(bbuf, gcursor, bbase, offp, csr);
  k_bounds<<<NB, 256, 0, stream>>>(batch, bound);

  // ---- layer 0 ----
  k_agg<<<AB, 256, 0, stream>>>(x, offp, csr, B1);
  k_sage_linear<<<GB3, 256, 0, stream>>>(B1, x, c0_Wl, c0_bl, c0_Wr, batch, gsum0, gsq0, B2);
  // z1 = LN0(B2) + x@s0_W
  k_skip_linear<<<GB3, 256, 0, stream>>>(x, s0_W,
                                         B2, gsum0, gsq0, ln0_w, ln0_b, p0_a,
                                         nullptr, nullptr, nullptr, nullptr, nullptr, nullptr,
                                         batch, bound, B3);

  // ---- layer 1 ----
  k_agg<<<AB, 256, 0, stream>>>(B3, offp, csr, B1);
  k_sage_linear<<<GB3, 256, 0, stream>>>(B1, B3, c1_Wl, c1_bl, c1_Wr, batch, gsum1, gsq1, B4);
  // z2 = LN0(B2) + LN1(B4) + x@s1_W
  k_skip_linear<<<GB3, 256, 0, stream>>>(x, s1_W,
                                         B2, gsum0, gsq0, ln0_w, ln0_b, p0_a,
                                         B4, gsum1, gsq1, ln1_w, ln1_b, p1_a,
                                         batch, bound, B3);

  // ---- layer 2 ----
  k_agg<<<AB, 256, 0, stream>>>(B3, offp, csr, B1);
  k_sage_linear<<<GB3, 256, 0, stream>>>(B1, B3, c2_Wl, c2_bl, c2_Wr, batch, gsum2, gsq2, out);
  k_ln_apply<<<WB, 256, 0, stream>>>(out, batch, bound, gsum2, gsq2, ln2_w, ln2_b, p2_a, out);
}

// Round 9
// 245.848 us; speedup vs baseline: 1.0486x; 1.0486x over previous
//
#include <hip/hip_runtime.h>

#define NN 50000
#define NE 800000
#define NG 128
#define NF 64
#define EPSV 1e-5f
#define GB3 782     // GEMM blocks = ceil(NN/64)
#define NBUCK 196   // node buckets of 256
#define BCAP 5120   // bucket capacity (mean 4096, sigma~64)

// ======================= zero init =======================
__global__ __launch_bounds__(256) void k_zero(int* __restrict__ gcursor,
                                              float* __restrict__ stats) {
  int t = threadIdx.x;
  if (t < NBUCK) gcursor[t] = 0;
  for (int i = t; i < 6 * NG; i += 256) stats[i] = 0.f;
}

// ======================= bucketed CSR build =======================
__global__ __launch_bounds__(256) void k_binA(const int* __restrict__ src,
                                              const int* __restrict__ dst,
                                              int* __restrict__ gcursor,
                                              int2* __restrict__ bbuf) {
  __shared__ int cnt[NBUCK], base[NBUCK], rank[NBUCK];
  int tid = threadIdx.x;
  if (tid < NBUCK) { cnt[tid] = 0; rank[tid] = 0; }
  __syncthreads();
  int e0 = blockIdx.x * 4096;
  int sv[16], dv[16], bk[16];
#pragma unroll
  for (int i = 0; i < 16; ++i) {
    int e = e0 + i * 256 + tid;
    if (e < NE) {
      sv[i] = src[e];
      dv[i] = dst[e];
      bk[i] = dv[i] >> 8;
      atomicAdd(&cnt[bk[i]], 1);
    } else bk[i] = -1;
  }
  __syncthreads();
  if (tid < NBUCK && cnt[tid] > 0) base[tid] = atomicAdd(&gcursor[tid], cnt[tid]);
  __syncthreads();
#pragma unroll
  for (int i = 0; i < 16; ++i) {
    if (bk[i] >= 0) {
      int p = base[bk[i]] + atomicAdd(&rank[bk[i]], 1);
      if (p < BCAP) bbuf[(size_t)bk[i] * BCAP + p] = make_int2(sv[i], dv[i]);
    }
  }
}

__global__ __launch_bounds__(256) void k_bscan(const int* __restrict__ gcursor,
                                               int* __restrict__ bbase,
                                               int* __restrict__ off) {
  __shared__ int sh[256];
  int tid = threadIdx.x;
  int v = (tid < NBUCK) ? gcursor[tid] : 0;
  sh[tid] = v;
  __syncthreads();
  for (int d = 1; d < 256; d <<= 1) {
    int t = (tid >= d) ? sh[tid - d] : 0;
    __syncthreads();
    sh[tid] += t;
    __syncthreads();
  }
  if (tid < NBUCK) bbase[tid] = sh[tid] - v;
  if (tid == NBUCK - 1) { bbase[NBUCK] = sh[tid]; off[NN] = sh[tid]; }
}

__global__ __launch_bounds__(256) void k_binB(const int2* __restrict__ bbuf,
                                              const int* __restrict__ gcursor,
                                              const int* __restrict__ bbase,
                                              int* __restrict__ off,
                                              int* __restrict__ csr) {
  __shared__ int cnt[256], cur[256], sh[256];
  int tid = threadIdx.x;
  int b = blockIdx.x;
  int nb = gcursor[b]; if (nb > BCAP) nb = BCAP;
  int gbase = bbase[b];
  cnt[tid] = 0;
  __syncthreads();
  const int2* bp = bbuf + (size_t)b * BCAP;
  for (int i = tid; i < nb; i += 256) {
    atomicAdd(&cnt[bp[i].y & 255], 1);
  }
  __syncthreads();
  int v = cnt[tid];
  sh[tid] = v;
  __syncthreads();
  for (int d = 1; d < 256; d <<= 1) {
    int t = (tid >= d) ? sh[tid - d] : 0;
    __syncthreads();
    sh[tid] += t;
    __syncthreads();
  }
  int excl = sh[tid] - v;
  cur[tid] = excl;
  int node = b * 256 + tid;
  if (node < NN) off[node] = gbase + excl;
  __syncthreads();
  for (int i = tid; i < nb; i += 256) {
    int2 e = bp[i];
    int p = atomicAdd(&cur[e.y & 255], 1);
    csr[gbase + p] = e.x;
  }
}

// graph boundaries from sorted batch
__global__ void k_bounds(const int* __restrict__ batch, int* __restrict__ bound) {
  int i = blockIdx.x * 256 + threadIdx.x;
  if (i >= NN) return;
  int b1 = batch[i];
  int b0 = (i == 0) ? -1 : batch[i - 1];
  for (int g = b0 + 1; g <= b1; ++g) bound[g] = i;
  if (i == NN - 1) {
    for (int g = b1 + 1; g <= NG; ++g) bound[g] = NN;
  }
}

// ============ mean aggregation: 1 wave/node, 4 edge-slots x 16 feature lanes ============
// Serial chain per node drops from deg to ceil(deg/4); 4 row-gathers in flight per wave.
__global__ __launch_bounds__(256) void k_agg(const float* __restrict__ in,
                                             const int* __restrict__ off,
                                             const int* __restrict__ csr,
                                             float* __restrict__ out) {
  int t = blockIdx.x * 256 + threadIdx.x;
  int node = t >> 6;
  int lane = threadIdx.x & 63;
  int eo = lane >> 4;            // edge slot 0..3
  int fl = (lane & 15) << 2;     // float4 feature offset
  if (node >= NN) return;
  int s0 = off[node], s1 = off[node + 1];
  float4 acc = make_float4(0.f, 0.f, 0.f, 0.f);
  for (int j = s0 + eo; j < s1; j += 4) {
    int s = csr[j];
    float4 v = *(const float4*)&in[(size_t)s * NF + fl];
    acc.x += v.x; acc.y += v.y; acc.z += v.z; acc.w += v.w;
  }
  // combine 4 edge-slot partials (feature lane alignment preserved)
  acc.x += __shfl_xor(acc.x, 16); acc.y += __shfl_xor(acc.y, 16);
  acc.z += __shfl_xor(acc.z, 16); acc.w += __shfl_xor(acc.w, 16);
  acc.x += __shfl_xor(acc.x, 32); acc.y += __shfl_xor(acc.y, 32);
  acc.z += __shfl_xor(acc.z, 32); acc.w += __shfl_xor(acc.w, 32);
  if (eo == 0) {
    int d = s1 - s0;
    float inv = (d > 0) ? 1.f / (float)d : 0.f;
    *(float4*)&out[(size_t)node * NF + fl] =
        make_float4(acc.x * inv, acc.y * inv, acc.z * inv, acc.w * inv);
  }
}

// ============ dual GEMM: lane=row, wave=16-col slice; fused LN stats ============
__global__ __launch_bounds__(256) void k_sage_linear(const float* __restrict__ A,
                                                     const float* __restrict__ X,
                                                     const float* __restrict__ Wl,
                                                     const float* __restrict__ bl,
                                                     const float* __restrict__ Wr,
                                                     const int* __restrict__ batch,
                                                     float* __restrict__ gsum,
                                                     float* __restrict__ gsq,
                                                     float* __restrict__ out) {
  __shared__ float sh_s[4][64];
  __shared__ float sh_q[4][64];
  __shared__ float gs[NG];
  __shared__ float gq[NG];
  int tid = threadIdx.x;
  int lane = tid & 63;
  int wv = __builtin_amdgcn_readfirstlane(tid >> 6);
  int c0 = wv * 16;
  int row = blockIdx.x * 64 + lane;
  bool valid = row < NN;
  if (tid < NG) { gs[tid] = 0.f; gq[tid] = 0.f; }

  float acc[16];
#pragma unroll
  for (int cc = 0; cc < 16; ++cc) acc[cc] = bl[c0 + cc];

  int rsafe = valid ? row : 0;
  const float4* Ar = (const float4*)(A + (size_t)rsafe * NF);
  const float4* Xr = (const float4*)(X + (size_t)rsafe * NF);

  for (int k4 = 0; k4 < 16; ++k4) {
    float4 av = Ar[k4];
    const float* W0 = Wl + ((k4 * 4 + 0) * NF + c0);
    const float* W1 = Wl + ((k4 * 4 + 1) * NF + c0);
    const float* W2 = Wl + ((k4 * 4 + 2) * NF + c0);
    const float* W3 = Wl + ((k4 * 4 + 3) * NF + c0);
#pragma unroll
    for (int cc = 0; cc < 16; ++cc)
      acc[cc] += av.x * W0[cc] + av.y * W1[cc] + av.z * W2[cc] + av.w * W3[cc];
  }
  for (int k4 = 0; k4 < 16; ++k4) {
    float4 xv = Xr[k4];
    const float* W0 = Wr + ((k4 * 4 + 0) * NF + c0);
    const float* W1 = Wr + ((k4 * 4 + 1) * NF + c0);
    const float* W2 = Wr + ((k4 * 4 + 2) * NF + c0);
    const float* W3 = Wr + ((k4 * 4 + 3) * NF + c0);
#pragma unroll
    for (int cc = 0; cc < 16; ++cc)
      acc[cc] += xv.x * W0[cc] + xv.y * W1[cc] + xv.z * W2[cc] + xv.w * W3[cc];
  }

  if (valid) {
    float4* op = (float4*)(out + (size_t)row * NF + c0);
    op[0] = make_float4(acc[0], acc[1], acc[2], acc[3]);
    op[1] = make_float4(acc[4], acc[5], acc[6], acc[7]);
    op[2] = make_float4(acc[8], acc[9], acc[10], acc[11]);
    op[3] = make_float4(acc[12], acc[13], acc[14], acc[15]);
  }

  float s = 0.f, q = 0.f;
#pragma unroll
  for (int cc = 0; cc < 16; ++cc) { s += acc[cc]; q += acc[cc] * acc[cc]; }
  sh_s[wv][lane] = s;
  sh_q[wv][lane] = q;
  __syncthreads();
  if (tid < 64) {
    float ss = sh_s[0][lane] + sh_s[1][lane] + sh_s[2][lane] + sh_s[3][lane];
    float qq = sh_q[0][lane] + sh_q[1][lane] + sh_q[2][lane] + sh_q[3][lane];
    int r = blockIdx.x * 64 + lane;
    if (r < NN) {
      int g = batch[r];
      atomicAdd(&gs[g], ss);
      atomicAdd(&gq[g], qq);
    }
  }
  __syncthreads();
  if (tid < NG) {
    float fs = gs[tid], fq = gq[tid];
    if (fs != 0.f || fq != 0.f) { atomicAdd(&gsum[tid], fs); atomicAdd(&gsq[tid], fq); }
  }
}

// ============ skip GEMM: out = LN0(t0) [+ LN1(t1)] + X@W  (lane=row) ============
__global__ __launch_bounds__(256) void k_skip_linear(
    const float* __restrict__ X, const float* __restrict__ W,
    const float* __restrict__ t0, const float* __restrict__ gsum0, const float* __restrict__ gsq0,
    const float* __restrict__ lw0, const float* __restrict__ lb0, const float* __restrict__ pa0,
    const float* __restrict__ t1, const float* __restrict__ gsum1, const float* __restrict__ gsq1,
    const float* __restrict__ lw1, const float* __restrict__ lb1, const float* __restrict__ pa1,
    const int* __restrict__ batch, const int* __restrict__ bound,
    float* __restrict__ out) {
  int tid = threadIdx.x;
  int lane = tid & 63;
  int wv = __builtin_amdgcn_readfirstlane(tid >> 6);
  int c0 = wv * 16;
  int row = blockIdx.x * 64 + lane;
  bool valid = row < NN;
  int rsafe = valid ? row : 0;

  float acc[16];
#pragma unroll
  for (int cc = 0; cc < 16; ++cc) acc[cc] = 0.f;

  const float4* Xr = (const float4*)(X + (size_t)rsafe * NF);
  for (int k4 = 0; k4 < 16; ++k4) {
    float4 xv = Xr[k4];
    const float* W0 = W + ((k4 * 4 + 0) * NF + c0);
    const float* W1 = W + ((k4 * 4 + 1) * NF + c0);
    const float* W2 = W + ((k4 * 4 + 2) * NF + c0);
    const float* W3 = W + ((k4 * 4 + 3) * NF + c0);
#pragma unroll
    for (int cc = 0; cc < 16; ++cc)
      acc[cc] += xv.x * W0[cc] + xv.y * W1[cc] + xv.z * W2[cc] + xv.w * W3[cc];
  }

  int g = batch[rsafe];
  float cntf = (float)(bound[g + 1] - bound[g]);
  float norm = fmaxf(cntf, 1.f) * (float)NF;
  {
    float m0 = gsum0[g] / norm;
    float v0 = gsq0[g] / norm - m0 * m0;
    float rs0 = rsqrtf(v0 + EPSV);
    float a0 = pa0[0];
    const float4* T0 = (const float4*)(t0 + (size_t)rsafe * NF + c0);
#pragma unroll
    for (int j = 0; j < 4; ++j) {
      float4 tv = T0[j];
      float tvv[4] = {tv.x, tv.y, tv.z, tv.w};
#pragma unroll
      for (int jj = 0; jj < 4; ++jj) {
        int cc = j * 4 + jj;
        float u = (tvv[jj] - m0) * rs0 * lw0[c0 + cc] + lb0[c0 + cc];
        acc[cc] += (u >= 0.f) ? u : a0 * u;
      }
    }
  }
  if (t1) {
    float m1 = gsum1[g] / norm;
    float v1 = gsq1[g] / norm - m1 * m1;
    float rs1 = rsqrtf(v1 + EPSV);
    float a1 = pa1[0];
    const float4* T1 = (const float4*)(t1 + (size_t)rsafe * NF + c0);
#pragma unroll
    for (int j = 0; j < 4; ++j) {
      float4 tv = T1[j];
      float tvv[4] = {tv.x, tv.y, tv.z, tv.w};
#pragma unroll
      for (int jj = 0; jj < 4; ++jj) {
        int cc = j * 4 + jj;
        float u = (tvv[jj] - m1) * rs1 * lw1[c0 + cc] + lb1[c0 + cc];
        acc[cc] += (u >= 0.f) ? u : a1 * u;
      }
    }
  }

  if (valid) {
    float4* op = (float4*)(out + (size_t)row * NF + c0);
    op[0] = make_float4(acc[0], acc[1], acc[2], acc[3]);
    op[1] = make_float4(acc[4], acc[5], acc[6], acc[7]);
    op[2] = make_float4(acc[8], acc[9], acc[10], acc[11]);
    op[3] = make_float4(acc[12], acc[13], acc[14], acc[15]);
  }
}

// ============ graph LayerNorm apply + affine + PReLU (final layer) ============
__global__ __launch_bounds__(256) void k_ln_apply(const float* __restrict__ t,
                                                  const int* __restrict__ batch,
                                                  const int* __restrict__ bound,
                                                  const float* __restrict__ gsum,
                                                  const float* __restrict__ gsq,
                                                  const float* __restrict__ w,
                                                  const float* __restrict__ b,
                                                  const float* __restrict__ alpha,
                                                  float* __restrict__ out) {
  int wid = (blockIdx.x * 256 + threadIdx.x) >> 6;
  int lane = threadIdx.x & 63;
  if (wid >= NN) return;
  int g = batch[wid];
  float cnt = (float)(bound[g + 1] - bound[g]);
  float norm = fmaxf(cnt, 1.f) * (float)NF;
  float mean = gsum[g] / norm;
  float var = gsq[g] / norm - mean * mean;
  float rstd = rsqrtf(var + EPSV);
  float a = alpha[0];
  float v = t[wid * NF + lane];
  v = (v - mean) * rstd;
  v = v * w[lane] + b[lane];
  out[wid * NF + lane] = (v >= 0.f) ? v : a * v;
}

// ======================= launch =======================
extern "C" void kernel_launch(void* const* d_in, const int* in_sizes, int n_in,
                              void* d_out, int out_size, void* d_ws, size_t ws_size,
                              hipStream_t stream) {
  const float* x     = (const float*)d_in[0];
  const float* c0_Wl = (const float*)d_in[1];
  const float* c0_bl = (const float*)d_in[2];
  const float* c0_Wr = (const float*)d_in[3];
  const float* c1_Wl = (const float*)d_in[4];
  const float* c1_bl = (const float*)d_in[5];
  const float* c1_Wr = (const float*)d_in[6];
  const float* c2_Wl = (const float*)d_in[7];
  const float* c2_bl = (const float*)d_in[8];
  const float* c2_Wr = (const float*)d_in[9];
  const float* s0_W  = (const float*)d_in[10];
  const float* s1_W  = (const float*)d_in[11];
  const float* ln0_w = (const float*)d_in[12];
  const float* ln0_b = (const float*)d_in[13];
  const float* ln1_w = (const float*)d_in[14];
  const float* ln1_b = (const float*)d_in[15];
  const float* ln2_w = (const float*)d_in[16];
  const float* ln2_b = (const float*)d_in[17];
  const float* p0_a  = (const float*)d_in[18];
  const float* p1_a  = (const float*)d_in[19];
  const float* p2_a  = (const float*)d_in[20];
  const int*   ei    = (const int*)d_in[21];   // [2, E] int32
  const int*   batch = (const int*)d_in[22];   // [N] int32
  float* out = (float*)d_out;

  const int* src = ei;
  const int* dst = ei + NE;

  // ---- workspace layout ----
  char* ws = (char*)d_ws;
  const size_t off_gcur   = 0;                          // NBUCK ints
  const size_t off_stats  = 200704;                     // 6*G floats
  const size_t off_bound  = 204800;                     // G+1 ints
  const size_t off_off    = 205824;                     // N+1 ints
  const size_t off_bbase  = 406272;                     // NBUCK+1 ints
  const size_t off_csr    = 607744;                     // E ints
  const size_t off_B1     = 3807744;                    // N*F floats (bbuf aliases)
  const size_t off_B2     = off_B1 + 12800000;
  const size_t off_B3     = off_B2 + 12800000;
  const size_t off_B4     = off_B3 + 12800000;

  int*   gcursor = (int*)(ws + off_gcur);
  float* stats   = (float*)(ws + off_stats);
  int*   bound   = (int*)(ws + off_bound);
  int*   offp    = (int*)(ws + off_off);
  int*   bbase   = (int*)(ws + off_bbase);
  int*   csr     = (int*)(ws + off_csr);
  float* B1      = (float*)(ws + off_B1);   // agg output (after CSR build)
  int2*  bbuf    = (int2*)(ws + off_B1);    // edge buckets (dead after binB)
  float* B2      = (float*)(ws + off_B2);   // h1 (raw pre-LN)
  float* B3      = (float*)(ws + off_B3);   // z
  float* B4      = (float*)(ws + off_B4);   // h2 (raw pre-LN)
  (void)ws_size; (void)in_sizes; (void)n_in; (void)out_size;

  float* gsum0 = stats + 0 * NG; float* gsq0 = stats + 1 * NG;
  float* gsum1 = stats + 2 * NG; float* gsq1 = stats + 3 * NG;
  float* gsum2 = stats + 4 * NG; float* gsq2 = stats + 5 * NG;

  const int NB  = (NN + 255) / 256;            // 196
  const int WB  = (NN * 64 + 255) / 256;       // 12500 (wave-per-node)
  const int AB4 = (NN * 64 + 255) / 256;       // 12500 (agg: wave per node)

  // zero init
  k_zero<<<1, 256, 0, stream>>>(gcursor, stats);

  // bucketed CSR build (once, reused by all 3 layers)
  k_binA<<<NBUCK, 256, 0, stream>>>(src, dst, gcursor, bbuf);
  k_bscan<<<1, 256, 0, stream>>>(gcursor, bbase, offp);
  k_binB<<<NBUCK, 256, 0, stream>>>(bbuf, gcursor, bbase, offp, csr);
  k_bounds<<<NB, 256, 0, stream>>>(batch, bound);

  // ---- layer 0 ----
  k_agg<<<AB4, 256, 0, stream>>>(x, offp, csr, B1);
  k_sage_linear<<<GB3, 256, 0, stream>>>(B1, x, c0_Wl, c0_bl, c0_Wr, batch, gsum0, gsq0, B2);
  // z1 = LN0(B2) + x@s0_W
  k_skip_linear<<<GB3, 256, 0, stream>>>(x, s0_W,
                                         B2, gsum0, gsq0, ln0_w, ln0_b, p0_a,
                                         nullptr, nullptr, nullptr, nullptr, nullptr, nullptr,
                                         batch, bound, B3);

  // ---- layer 1 ----
  k_agg<<<AB4, 256, 0, stream>>>(B3, offp, csr, B1);
  k_sage_linear<<<GB3, 256, 0, stream>>>(B1, B3, c1_Wl, c1_bl, c1_Wr, batch, gsum1, gsq1, B4);
  // z2 = LN0(B2) + LN1(B4) + x@s1_W
  k_skip_linear<<<GB3, 256, 0, stream>>>(x, s1_W,
                                         B2, gsum0, gsq0, ln0_w, ln0_b, p0_a,
                                         B4, gsum1, gsq1, ln1_w, ln1_b, p1_a,
                                         batch, bound, B3);

  // ---- layer 2 ----
  k_agg<<<AB4, 256, 0, stream>>>(B3, offp, csr, B1);
  k_sage_linear<<<GB3, 256, 0, stream>>>(B1, B3, c2_Wl, c2_bl, c2_Wr, batch, gsum2, gsq2, out);
  k_ln_apply<<<WB, 256, 0, stream>>>(out, batch, bound, gsum2, gsq2, ln2_w, ln2_b, p2_a, out);
}

// Round 10
// 223.461 us; speedup vs baseline: 1.1537x; 1.1002x over previous
//
#include <hip/hip_runtime.h>

#define NN 50000
#define NE 800000
#define NG 128
#define NF 64
#define EPSV 1e-5f
#define GB3 782     // GEMM blocks = ceil(NN/64)
#define NBUCK 196   // node buckets of 256
#define BCAP 5120   // bucket capacity (mean 4096, sigma~64)

typedef unsigned short ushortT;

__device__ inline unsigned short f2bf(float f) {
  unsigned u = __float_as_uint(f);
  u += 0x7FFF + ((u >> 16) & 1);          // round-to-nearest-even
  return (unsigned short)(u >> 16);
}

// ======================= bounds + zero init (merged) =======================
__global__ void k_bz(const int* __restrict__ batch, int* __restrict__ bound,
                     int* __restrict__ gcursor, float* __restrict__ stats) {
  int i = blockIdx.x * 256 + threadIdx.x;
  if (blockIdx.x == 0) {
    int t = threadIdx.x;
    if (t < NBUCK) gcursor[t] = 0;
    for (int k = t; k < 6 * NG; k += 256) stats[k] = 0.f;
  }
  if (i >= NN) return;
  int b1 = batch[i];
  int b0 = (i == 0) ? -1 : batch[i - 1];
  for (int g = b0 + 1; g <= b1; ++g) bound[g] = i;
  if (i == NN - 1) {
    for (int g = b1 + 1; g <= NG; ++g) bound[g] = NN;
  }
}

// ======================= fp32 -> bf16 conversion (x, once) =======================
__global__ __launch_bounds__(256) void k_cvt(const float* __restrict__ in,
                                             ushortT* __restrict__ outb) {
  int t = blockIdx.x * 256 + threadIdx.x;      // one float4 per thread
  if (t >= NN * NF / 4) return;
  float4 v = ((const float4*)in)[t];
  ushortT4_t: ;
  ushort4 o;
  o.x = f2bf(v.x); o.y = f2bf(v.y); o.z = f2bf(v.z); o.w = f2bf(v.w);
  ((ushort4*)outb)[t] = o;
}

// ======================= bucketed CSR build =======================
__global__ __launch_bounds__(256) void k_binA(const int* __restrict__ src,
                                              const int* __restrict__ dst,
                                              int* __restrict__ gcursor,
                                              int2* __restrict__ bbuf) {
  __shared__ int cnt[NBUCK], base[NBUCK], rank[NBUCK];
  int tid = threadIdx.x;
  if (tid < NBUCK) { cnt[tid] = 0; rank[tid] = 0; }
  __syncthreads();
  int e0 = blockIdx.x * 4096;
  int sv[16], dv[16], bk[16];
#pragma unroll
  for (int i = 0; i < 16; ++i) {
    int e = e0 + i * 256 + tid;
    if (e < NE) {
      sv[i] = src[e];
      dv[i] = dst[e];
      bk[i] = dv[i] >> 8;
      atomicAdd(&cnt[bk[i]], 1);
    } else bk[i] = -1;
  }
  __syncthreads();
  if (tid < NBUCK && cnt[tid] > 0) base[tid] = atomicAdd(&gcursor[tid], cnt[tid]);
  __syncthreads();
#pragma unroll
  for (int i = 0; i < 16; ++i) {
    if (bk[i] >= 0) {
      int p = base[bk[i]] + atomicAdd(&rank[bk[i]], 1);
      if (p < BCAP) bbuf[(size_t)bk[i] * BCAP + p] = make_int2(sv[i], dv[i]);
    }
  }
}

__global__ __launch_bounds__(256) void k_bscan(const int* __restrict__ gcursor,
                                               int* __restrict__ bbase,
                                               int* __restrict__ off) {
  __shared__ int sh[256];
  int tid = threadIdx.x;
  int v = (tid < NBUCK) ? gcursor[tid] : 0;
  sh[tid] = v;
  __syncthreads();
  for (int d = 1; d < 256; d <<= 1) {
    int t = (tid >= d) ? sh[tid - d] : 0;
    __syncthreads();
    sh[tid] += t;
    __syncthreads();
  }
  if (tid < NBUCK) bbase[tid] = sh[tid] - v;
  if (tid == NBUCK - 1) { bbase[NBUCK] = sh[tid]; off[NN] = sh[tid]; }
}

__global__ __launch_bounds__(256) void k_binB(const int2* __restrict__ bbuf,
                                              const int* __restrict__ gcursor,
                                              const int* __restrict__ bbase,
                                              int* __restrict__ off,
                                              int* __restrict__ csr) {
  __shared__ int cnt[256], cur[256], sh[256];
  int tid = threadIdx.x;
  int b = blockIdx.x;
  int nb = gcursor[b]; if (nb > BCAP) nb = BCAP;
  int gbase = bbase[b];
  cnt[tid] = 0;
  __syncthreads();
  const int2* bp = bbuf + (size_t)b * BCAP;
  for (int i = tid; i < nb; i += 256) {
    atomicAdd(&cnt[bp[i].y & 255], 1);
  }
  __syncthreads();
  int v = cnt[tid];
  sh[tid] = v;
  __syncthreads();
  for (int d = 1; d < 256; d <<= 1) {
    int t = (tid >= d) ? sh[tid - d] : 0;
    __syncthreads();
    sh[tid] += t;
    __syncthreads();
  }
  int excl = sh[tid] - v;
  cur[tid] = excl;
  int node = b * 256 + tid;
  if (node < NN) off[node] = gbase + excl;
  __syncthreads();
  for (int i = tid; i < nb; i += 256) {
    int2 e = bp[i];
    int p = atomicAdd(&cur[e.y & 255], 1);
    csr[gbase + p] = e.x;
  }
}

// ============ mean aggregation: bf16 gather, 8 edge-slots x 8 lanes x 16B ============
__global__ __launch_bounds__(256) void k_agg(const ushortT* __restrict__ in,
                                             const int* __restrict__ off,
                                             const int* __restrict__ csr,
                                             float* __restrict__ out) {
  int t = blockIdx.x * 256 + threadIdx.x;
  int node = t >> 6;
  int lane = threadIdx.x & 63;
  int eo = lane >> 3;            // edge slot 0..7
  int fl = (lane & 7) << 3;      // 8-feature base
  if (node >= NN) return;
  int s0 = off[node], s1 = off[node + 1];
  float a0 = 0.f, a1 = 0.f, a2 = 0.f, a3 = 0.f, a4 = 0.f, a5 = 0.f, a6 = 0.f, a7 = 0.f;
  for (int j = s0 + eo; j < s1; j += 8) {
    int s = csr[j];
    uint4 v = *(const uint4*)&in[(size_t)s * NF + fl];   // 8 bf16 = 16B
    a0 += __uint_as_float(v.x << 16);
    a1 += __uint_as_float(v.x & 0xFFFF0000u);
    a2 += __uint_as_float(v.y << 16);
    a3 += __uint_as_float(v.y & 0xFFFF0000u);
    a4 += __uint_as_float(v.z << 16);
    a5 += __uint_as_float(v.z & 0xFFFF0000u);
    a6 += __uint_as_float(v.w << 16);
    a7 += __uint_as_float(v.w & 0xFFFF0000u);
  }
#pragma unroll
  for (int d = 8; d < 64; d <<= 1) {
    a0 += __shfl_xor(a0, d); a1 += __shfl_xor(a1, d);
    a2 += __shfl_xor(a2, d); a3 += __shfl_xor(a3, d);
    a4 += __shfl_xor(a4, d); a5 += __shfl_xor(a5, d);
    a6 += __shfl_xor(a6, d); a7 += __shfl_xor(a7, d);
  }
  if (eo == 0) {
    int dg = s1 - s0;
    float inv = (dg > 0) ? 1.f / (float)dg : 0.f;
    float4* op = (float4*)&out[(size_t)node * NF + fl];
    op[0] = make_float4(a0 * inv, a1 * inv, a2 * inv, a3 * inv);
    op[1] = make_float4(a4 * inv, a5 * inv, a6 * inv, a7 * inv);
  }
}

// ============ dual GEMM: lane=row, wave=16-col slice; fused LN stats ============
__global__ __launch_bounds__(256) void k_sage_linear(const float* __restrict__ A,
                                                     const float* __restrict__ X,
                                                     const float* __restrict__ Wl,
                                                     const float* __restrict__ bl,
                                                     const float* __restrict__ Wr,
                                                     const int* __restrict__ batch,
                                                     float* __restrict__ gsum,
                                                     float* __restrict__ gsq,
                                                     float* __restrict__ out) {
  __shared__ float sh_s[4][64];
  __shared__ float sh_q[4][64];
  __shared__ float gs[NG];
  __shared__ float gq[NG];
  int tid = threadIdx.x;
  int lane = tid & 63;
  int wv = __builtin_amdgcn_readfirstlane(tid >> 6);
  int c0 = wv * 16;
  int row = blockIdx.x * 64 + lane;
  bool valid = row < NN;
  if (tid < NG) { gs[tid] = 0.f; gq[tid] = 0.f; }

  float acc[16];
#pragma unroll
  for (int cc = 0; cc < 16; ++cc) acc[cc] = bl[c0 + cc];

  int rsafe = valid ? row : 0;
  const float4* Ar = (const float4*)(A + (size_t)rsafe * NF);
  const float4* Xr = (const float4*)(X + (size_t)rsafe * NF);

  for (int k4 = 0; k4 < 16; ++k4) {
    float4 av = Ar[k4];
    const float* W0 = Wl + ((k4 * 4 + 0) * NF + c0);
    const float* W1 = Wl + ((k4 * 4 + 1) * NF + c0);
    const float* W2 = Wl + ((k4 * 4 + 2) * NF + c0);
    const float* W3 = Wl + ((k4 * 4 + 3) * NF + c0);
#pragma unroll
    for (int cc = 0; cc < 16; ++cc)
      acc[cc] += av.x * W0[cc] + av.y * W1[cc] + av.z * W2[cc] + av.w * W3[cc];
  }
  for (int k4 = 0; k4 < 16; ++k4) {
    float4 xv = Xr[k4];
    const float* W0 = Wr + ((k4 * 4 + 0) * NF + c0);
    const float* W1 = Wr + ((k4 * 4 + 1) * NF + c0);
    const float* W2 = Wr + ((k4 * 4 + 2) * NF + c0);
    const float* W3 = Wr + ((k4 * 4 + 3) * NF + c0);
#pragma unroll
    for (int cc = 0; cc < 16; ++cc)
      acc[cc] += xv.x * W0[cc] + xv.y * W1[cc] + xv.z * W2[cc] + xv.w * W3[cc];
  }

  if (valid) {
    float4* op = (float4*)(out + (size_t)row * NF + c0);
    op[0] = make_float4(acc[0], acc[1], acc[2], acc[3]);
    op[1] = make_float4(acc[4], acc[5], acc[6], acc[7]);
    op[2] = make_float4(acc[8], acc[9], acc[10], acc[11]);
    op[3] = make_float4(acc[12], acc[13], acc[14], acc[15]);
  }

  float s = 0.f, q = 0.f;
#pragma unroll
  for (int cc = 0; cc < 16; ++cc) { s += acc[cc]; q += acc[cc] * acc[cc]; }
  sh_s[wv][lane] = s;
  sh_q[wv][lane] = q;
  __syncthreads();
  if (tid < 64) {
    float ss = sh_s[0][lane] + sh_s[1][lane] + sh_s[2][lane] + sh_s[3][lane];
    float qq = sh_q[0][lane] + sh_q[1][lane] + sh_q[2][lane] + sh_q[3][lane];
    int r = blockIdx.x * 64 + lane;
    if (r < NN) {
      int g = batch[r];
      atomicAdd(&gs[g], ss);
      atomicAdd(&gq[g], qq);
    }
  }
  __syncthreads();
  if (tid < NG) {
    float fs = gs[tid], fq = gq[tid];
    if (fs != 0.f || fq != 0.f) { atomicAdd(&gsum[tid], fs); atomicAdd(&gsq[tid], fq); }
  }
}

// ============ skip GEMM: out = LN0(t0) [+ LN1(t1)] + X@W ; also bf16 copy ============
__global__ __launch_bounds__(256) void k_skip_linear(
    const float* __restrict__ X, const float* __restrict__ W,
    const float* __restrict__ t0, const float* __restrict__ gsum0, const float* __restrict__ gsq0,
    const float* __restrict__ lw0, const float* __restrict__ lb0, const float* __restrict__ pa0,
    const float* __restrict__ t1, const float* __restrict__ gsum1, const float* __restrict__ gsq1,
    const float* __restrict__ lw1, const float* __restrict__ lb1, const float* __restrict__ pa1,
    const int* __restrict__ batch, const int* __restrict__ bound,
    float* __restrict__ out, ushortT* __restrict__ outb) {
  int tid = threadIdx.x;
  int lane = tid & 63;
  int wv = __builtin_amdgcn_readfirstlane(tid >> 6);
  int c0 = wv * 16;
  int row = blockIdx.x * 64 + lane;
  bool valid = row < NN;
  int rsafe = valid ? row : 0;

  float acc[16];
#pragma unroll
  for (int cc = 0; cc < 16; ++cc) acc[cc] = 0.f;

  const float4* Xr = (const float4*)(X + (size_t)rsafe * NF);
  for (int k4 = 0; k4 < 16; ++k4) {
    float4 xv = Xr[k4];
    const float* W0 = W + ((k4 * 4 + 0) * NF + c0);
    const float* W1 = W + ((k4 * 4 + 1) * NF + c0);
    const float* W2 = W + ((k4 * 4 + 2) * NF + c0);
    const float* W3 = W + ((k4 * 4 + 3) * NF + c0);
#pragma unroll
    for (int cc = 0; cc < 16; ++cc)
      acc[cc] += xv.x * W0[cc] + xv.y * W1[cc] + xv.z * W2[cc] + xv.w * W3[cc];
  }

  int g = batch[rsafe];
  float cntf = (float)(bound[g + 1] - bound[g]);
  float norm = fmaxf(cntf, 1.f) * (float)NF;
  {
    float m0 = gsum0[g] / norm;
    float v0 = gsq0[g] / norm - m0 * m0;
    float rs0 = rsqrtf(v0 + EPSV);
    float a0 = pa0[0];
    const float4* T0 = (const float4*)(t0 + (size_t)rsafe * NF + c0);
#pragma unroll
    for (int j = 0; j < 4; ++j) {
      float4 tv = T0[j];
      float tvv[4] = {tv.x, tv.y, tv.z, tv.w};
#pragma unroll
      for (int jj = 0; jj < 4; ++jj) {
        int cc = j * 4 + jj;
        float u = (tvv[jj] - m0) * rs0 * lw0[c0 + cc] + lb0[c0 + cc];
        acc[cc] += (u >= 0.f) ? u : a0 * u;
      }
    }
  }
  if (t1) {
    float m1 = gsum1[g] / norm;
    float v1 = gsq1[g] / norm - m1 * m1;
    float rs1 = rsqrtf(v1 + EPSV);
    float a1 = pa1[0];
    const float4* T1 = (const float4*)(t1 + (size_t)rsafe * NF + c0);
#pragma unroll
    for (int j = 0; j < 4; ++j) {
      float4 tv = T1[j];
      float tvv[4] = {tv.x, tv.y, tv.z, tv.w};
#pragma unroll
      for (int jj = 0; jj < 4; ++jj) {
        int cc = j * 4 + jj;
        float u = (tvv[jj] - m1) * rs1 * lw1[c0 + cc] + lb1[c0 + cc];
        acc[cc] += (u >= 0.f) ? u : a1 * u;
      }
    }
  }

  if (valid) {
    float4* op = (float4*)(out + (size_t)row * NF + c0);
    op[0] = make_float4(acc[0], acc[1], acc[2], acc[3]);
    op[1] = make_float4(acc[4], acc[5], acc[6], acc[7]);
    op[2] = make_float4(acc[8], acc[9], acc[10], acc[11]);
    op[3] = make_float4(acc[12], acc[13], acc[14], acc[15]);
    // bf16 rail for the next layer's aggregation gather
    uint4 b0, b1v;
    b0.x = (unsigned)f2bf(acc[0]) | ((unsigned)f2bf(acc[1]) << 16);
    b0.y = (unsigned)f2bf(acc[2]) | ((unsigned)f2bf(acc[3]) << 16);
    b0.z = (unsigned)f2bf(acc[4]) | ((unsigned)f2bf(acc[5]) << 16);
    b0.w = (unsigned)f2bf(acc[6]) | ((unsigned)f2bf(acc[7]) << 16);
    b1v.x = (unsigned)f2bf(acc[8]) | ((unsigned)f2bf(acc[9]) << 16);
    b1v.y = (unsigned)f2bf(acc[10]) | ((unsigned)f2bf(acc[11]) << 16);
    b1v.z = (unsigned)f2bf(acc[12]) | ((unsigned)f2bf(acc[13]) << 16);
    b1v.w = (unsigned)f2bf(acc[14]) | ((unsigned)f2bf(acc[15]) << 16);
    uint4* obp = (uint4*)&outb[(size_t)row * NF + c0];
    obp[0] = b0;
    obp[1] = b1v;
  }
}

// ============ graph LayerNorm apply + affine + PReLU (final layer) ============
__global__ __launch_bounds__(256) void k_ln_apply(const float* __restrict__ t,
                                                  const int* __restrict__ batch,
                                                  const int* __restrict__ bound,
                                                  const float* __restrict__ gsum,
                                                  const float* __restrict__ gsq,
                                                  const float* __restrict__ w,
                                                  const float* __restrict__ b,
                                                  const float* __restrict__ alpha,
                                                  float* __restrict__ out) {
  int wid = (blockIdx.x * 256 + threadIdx.x) >> 6;
  int lane = threadIdx.x & 63;
  if (wid >= NN) return;
  int g = batch[wid];
  float cnt = (float)(bound[g + 1] - bound[g]);
  float norm = fmaxf(cnt, 1.f) * (float)NF;
  float mean = gsum[g] / norm;
  float var = gsq[g] / norm - mean * mean;
  float rstd = rsqrtf(var + EPSV);
  float a = alpha[0];
  float v = t[wid * NF + lane];
  v = (v - mean) * rstd;
  v = v * w[lane] + b[lane];
  out[wid * NF + lane] = (v >= 0.f) ? v : a * v;
}

// ======================= launch =======================
extern "C" void kernel_launch(void* const* d_in, const int* in_sizes, int n_in,
                              void* d_out, int out_size, void* d_ws, size_t ws_size,
                              hipStream_t stream) {
  const float* x     = (const float*)d_in[0];
  const float* c0_Wl = (const float*)d_in[1];
  const float* c0_bl = (const float*)d_in[2];
  const float* c0_Wr = (const float*)d_in[3];
  const float* c1_Wl = (const float*)d_in[4];
  const float* c1_bl = (const float*)d_in[5];
  const float* c1_Wr = (const float*)d_in[6];
  const float* c2_Wl = (const float*)d_in[7];
  const float* c2_bl = (const float*)d_in[8];
  const float* c2_Wr = (const float*)d_in[9];
  const float* s0_W  = (const float*)d_in[10];
  const float* s1_W  = (const float*)d_in[11];
  const float* ln0_w = (const float*)d_in[12];
  const float* ln0_b = (const float*)d_in[13];
  const float* ln1_w = (const float*)d_in[14];
  const float* ln1_b = (const float*)d_in[15];
  const float* ln2_w = (const float*)d_in[16];
  const float* ln2_b = (const float*)d_in[17];
  const float* p0_a  = (const float*)d_in[18];
  const float* p1_a  = (const float*)d_in[19];
  const float* p2_a  = (const float*)d_in[20];
  const int*   ei    = (const int*)d_in[21];   // [2, E] int32
  const int*   batch = (const int*)d_in[22];   // [N] int32
  float* out = (float*)d_out;

  const int* src = ei;
  const int* dst = ei + NE;

  // ---- workspace layout (ws_size ~256MB, confirmed by harness poison fills) ----
  char* ws = (char*)d_ws;
  const size_t off_gcur   = 0;                          // NBUCK ints
  const size_t off_stats  = 200704;                     // 6*G floats
  const size_t off_bound  = 204800;                     // G+1 ints
  const size_t off_off    = 205824;                     // N+1 ints
  const size_t off_bbase  = 406272;                     // NBUCK+1 ints
  const size_t off_csr    = 607744;                     // E ints
  const size_t off_B1     = 3807744;                    // N*F floats (bbuf aliases)
  const size_t off_B2     = off_B1 + 12800000;
  const size_t off_B3     = off_B2 + 12800000;
  const size_t off_B4     = off_B3 + 12800000;
  const size_t off_xb     = off_B4 + 12800000;          // N*F bf16 (x rail)
  const size_t off_B3b    = off_xb + 6400000;           // N*F bf16 (z rail)

  int*    gcursor = (int*)(ws + off_gcur);
  float*  stats   = (float*)(ws + off_stats);
  int*    bound   = (int*)(ws + off_bound);
  int*    offp    = (int*)(ws + off_off);
  int*    bbase   = (int*)(ws + off_bbase);
  int*    csr     = (int*)(ws + off_csr);
  float*  B1      = (float*)(ws + off_B1);   // agg output
  int2*   bbuf    = (int2*)(ws + off_B1);    // edge buckets (dead after binB)
  float*  B2      = (float*)(ws + off_B2);   // h1 (raw pre-LN)
  float*  B3      = (float*)(ws + off_B3);   // z (fp32)
  float*  B4      = (float*)(ws + off_B4);   // h2 (raw pre-LN)
  ushortT* xb     = (ushortT*)(ws + off_xb);  // x bf16 rail
  ushortT* B3b    = (ushortT*)(ws + off_B3b); // z bf16 rail
  (void)ws_size; (void)in_sizes; (void)n_in; (void)out_size;

  float* gsum0 = stats + 0 * NG; float* gsq0 = stats + 1 * NG;
  float* gsum1 = stats + 2 * NG; float* gsq1 = stats + 3 * NG;
  float* gsum2 = stats + 4 * NG; float* gsq2 = stats + 5 * NG;

  const int NB  = (NN + 255) / 256;            // 196
  const int WB  = (NN * 64 + 255) / 256;       // 12500 (wave-per-node)
  const int CB  = (NN * NF / 4 + 255) / 256;   // 3125  (cvt)

  // bounds + zero (merged), bf16 conversion of x, bucketed CSR build
  k_bz<<<NB, 256, 0, stream>>>(batch, bound, gcursor, stats);
  k_cvt<<<CB, 256, 0, stream>>>(x, xb);
  k_binA<<<NBUCK, 256, 0, stream>>>(src, dst, gcursor, bbuf);
  k_bscan<<<1, 256, 0, stream>>>(gcursor, bbase, offp);
  k_binB<<<NBUCK, 256, 0, stream>>>(bbuf, gcursor, bbase, offp, csr);

  // ---- layer 0 ----
  k_agg<<<WB, 256, 0, stream>>>(xb, offp, csr, B1);
  k_sage_linear<<<GB3, 256, 0, stream>>>(B1, x, c0_Wl, c0_bl, c0_Wr, batch, gsum0, gsq0, B2);
  // z1 = LN0(B2) + x@s0_W   (fp32 B3 + bf16 B3b)
  k_skip_linear<<<GB3, 256, 0, stream>>>(x, s0_W,
                                         B2, gsum0, gsq0, ln0_w, ln0_b, p0_a,
                                         nullptr, nullptr, nullptr, nullptr, nullptr, nullptr,
                                         batch, bound, B3, B3b);

  // ---- layer 1 ----
  k_agg<<<WB, 256, 0, stream>>>(B3b, offp, csr, B1);
  k_sage_linear<<<GB3, 256, 0, stream>>>(B1, B3, c1_Wl, c1_bl, c1_Wr, batch, gsum1, gsq1, B4);
  // z2 = LN0(B2) + LN1(B4) + x@s1_W
  k_skip_linear<<<GB3, 256, 0, stream>>>(x, s1_W,
                                         B2, gsum0, gsq0, ln0_w, ln0_b, p0_a,
                                         B4, gsum1, gsq1, ln1_w, ln1_b, p1_a,
                                         batch, bound, B3, B3b);

  // ---- layer 2 ----
  k_agg<<<WB, 256, 0, stream>>>(B3b, offp, csr, B1);
  k_sage_linear<<<GB3, 256, 0, stream>>>(B1, B3, c2_Wl, c2_bl, c2_Wr, batch, gsum2, gsq2, out);
  k_ln_apply<<<WB, 256, 0, stream>>>(out, batch, bound, gsum2, gsq2, ln2_w, ln2_b, p2_a, out);
}